// Round 2
// baseline (4547.738 us; speedup 1.0000x reference)
//
#include <hip/hip_runtime.h>
#include <math.h>

#define NN 100000
#define EE 1600000
#define CC 20
#define DD 8
#define GG 1024
#define LL 2
#define KK (2*CC+DD)   // 48
#define EPSV 1e-5f

#define SCAN_TPB 256
#define SCAN_ELEMS 4
#define NB 98                      // ceil(NN / 1024)
#define NPAD (NB * SCAN_TPB * SCAN_ELEMS)  // 100352

// ---------------- CSR build ----------------
__global__ __launch_bounds__(256) void k_hist(const int* __restrict__ ei,
                                              int* __restrict__ cnt) {
    int e = blockIdx.x * 256 + threadIdx.x;
    if (e >= EE) return;
    atomicAdd(&cnt[ei[EE + e]], 1);
}

__global__ __launch_bounds__(SCAN_TPB) void k_scan_a(const int* __restrict__ cnt,
                                                     int* __restrict__ offs,
                                                     int* __restrict__ bsum) {
    __shared__ int sdata[SCAN_TPB];
    int base = blockIdx.x * (SCAN_TPB * SCAN_ELEMS) + threadIdx.x * SCAN_ELEMS;
    int v[SCAN_ELEMS];
    int tot = 0;
#pragma unroll
    for (int i = 0; i < SCAN_ELEMS; ++i) {
        int idx = base + i;
        v[i] = (idx < NN) ? cnt[idx] : 0;
        tot += v[i];
    }
    sdata[threadIdx.x] = tot;
    __syncthreads();
    for (int o = 1; o < SCAN_TPB; o <<= 1) {
        int t = (threadIdx.x >= o) ? sdata[threadIdx.x - o] : 0;
        __syncthreads();
        sdata[threadIdx.x] += t;
        __syncthreads();
    }
    int run = sdata[threadIdx.x] - tot;  // exclusive prefix of this thread
#pragma unroll
    for (int i = 0; i < SCAN_ELEMS; ++i) {
        offs[base + i] = run;
        run += v[i];
    }
    if (threadIdx.x == SCAN_TPB - 1) bsum[blockIdx.x] = sdata[threadIdx.x];
}

__global__ __launch_bounds__(SCAN_TPB) void k_scan_b(int* __restrict__ bsum) {
    __shared__ int s[SCAN_TPB];
    int v = (threadIdx.x < NB) ? bsum[threadIdx.x] : 0;
    s[threadIdx.x] = v;
    __syncthreads();
    for (int o = 1; o < SCAN_TPB; o <<= 1) {
        int t = (threadIdx.x >= o) ? s[threadIdx.x - o] : 0;
        __syncthreads();
        s[threadIdx.x] += t;
        __syncthreads();
    }
    if (threadIdx.x < NB) bsum[threadIdx.x] = s[threadIdx.x] - v;  // exclusive
}

__global__ __launch_bounds__(256) void k_scan_c(int* __restrict__ offs,
                                                const int* __restrict__ bsum) {
    int i = blockIdx.x * 256 + threadIdx.x;   // grid = NPAD/256 exactly
    offs[i] += bsum[i >> 10];
}

__global__ __launch_bounds__(256) void k_fill(const int* __restrict__ ei,
                                              const int* __restrict__ offs,
                                              int* __restrict__ cur,
                                              int* __restrict__ elist) {
    int e = blockIdx.x * 256 + threadIdx.x;
    if (e >= EE) return;
    int d = ei[EE + e];
    int pos = atomicAdd(&cur[d], 1);
    elist[offs[d] + pos] = e;
}

// ---------------- fused edge-message + aggregate + residual ----------------
__device__ __forceinline__ void edge_compute(
    float4 x0, float4 x1, float4 x2, float4 x3, float4 x4,
    float4 e0, float4 e1,
    const float* __restrict__ sWf, const float* __restrict__ sWs,
    const float* f0, const float* g0, float* acc)
{
    float zz[28] = {x0.x, x0.y, x0.z, x0.w, x1.x, x1.y, x1.z, x1.w,
                    x2.x, x2.y, x2.z, x2.w, x3.x, x3.y, x3.z, x3.w,
                    x4.x, x4.y, x4.z, x4.w,
                    e0.x, e0.y, e0.z, e0.w, e1.x, e1.y, e1.z, e1.w};
    float f[CC], g[CC];
#pragma unroll
    for (int c = 0; c < CC; ++c) { f[c] = f0[c]; g[c] = g0[c]; }
#pragma unroll
    for (int k = 0; k < 28; ++k) {
        float zk = zz[k];
        int row = (CC + k) * CC;
#pragma unroll
        for (int c = 0; c < CC; ++c) {
            f[c] = fmaf(zk, sWf[row + c], f[c]);
            g[c] = fmaf(zk, sWs[row + c], g[c]);
        }
    }
#pragma unroll
    for (int c = 0; c < CC; ++c) {
        float sg = 1.0f / (1.0f + __expf(-f[c]));
        float a = fabsf(g[c]);
        float sp = fmaxf(g[c], 0.0f) + __logf(1.0f + __expf(-a));
        acc[c] += sg * sp;
    }
}

#define LOADZ(P, idx) do { \
    int e_ = elist[idx]; \
    int s_ = ei[e_]; \
    const float4* xp_ = reinterpret_cast<const float4*>(x + (size_t)s_ * CC); \
    P##x0 = xp_[0]; P##x1 = xp_[1]; P##x2 = xp_[2]; P##x3 = xp_[3]; P##x4 = xp_[4]; \
    const float4* ep_ = reinterpret_cast<const float4*>(ea + (size_t)e_ * DD); \
    P##e0 = ep_[0]; P##e1 = ep_[1]; \
} while (0)

__global__ __launch_bounds__(256, 1) void k_agg(
    const float* __restrict__ x, const int* __restrict__ ei,
    const float* __restrict__ ea,
    const int* __restrict__ offs, const int* __restrict__ elist,
    const float* __restrict__ wf, const float* __restrict__ bf,
    const float* __restrict__ wsm, const float* __restrict__ bs,
    float* __restrict__ y)
{
    __shared__ float sWf[KK * CC];
    __shared__ float sWs[KK * CC];
    __shared__ float sBf[CC];
    __shared__ float sBs[CC];
    for (int i = threadIdx.x; i < KK * CC; i += 256) {
        sWf[i] = wf[i];
        sWs[i] = wsm[i];
    }
    if (threadIdx.x < CC) {
        sBf[threadIdx.x] = bf[threadIdx.x];
        sBs[threadIdx.x] = bs[threadIdx.x];
    }
    __syncthreads();

    int n = blockIdx.x * 256 + threadIdx.x;
    if (n >= NN) return;

    // Per-node x_i contribution to both linear maps (hoisted out of edge loop)
    float f0[CC], g0[CC];
    {
        const float4* xp = reinterpret_cast<const float4*>(x + (size_t)n * CC);
        float xn[CC];
#pragma unroll
        for (int q = 0; q < 5; ++q) {
            float4 t = xp[q];
            xn[4*q+0] = t.x; xn[4*q+1] = t.y; xn[4*q+2] = t.z; xn[4*q+3] = t.w;
        }
#pragma unroll
        for (int c = 0; c < CC; ++c) { f0[c] = sBf[c]; g0[c] = sBs[c]; }
#pragma unroll
        for (int k = 0; k < CC; ++k) {
            float zk = xn[k];
#pragma unroll
            for (int c = 0; c < CC; ++c) {
                f0[c] = fmaf(zk, sWf[k*CC + c], f0[c]);
                g0[c] = fmaf(zk, sWs[k*CC + c], g0[c]);
            }
        }
    }

    float acc[CC];
#pragma unroll
    for (int c = 0; c < CC; ++c) acc[c] = 0.0f;

    int idx = offs[n];
    int end = offs[n + 1];   // NPAD-sized array: valid for n==NN-1 (pad counts are 0)

    float4 Ax0, Ax1, Ax2, Ax3, Ax4, Ae0, Ae1;
    float4 Bx0, Bx1, Bx2, Bx3, Bx4, Be0, Be1;
    if (idx < end) LOADZ(A, idx);
    while (idx < end) {
        int nxt = idx + 1;
        if (nxt < end) LOADZ(B, nxt);
        edge_compute(Ax0, Ax1, Ax2, Ax3, Ax4, Ae0, Ae1, sWf, sWs, f0, g0, acc);
        idx = nxt;
        if (idx >= end) break;
        nxt = idx + 1;
        if (nxt < end) LOADZ(A, nxt);
        edge_compute(Bx0, Bx1, Bx2, Bx3, Bx4, Be0, Be1, sWf, sWs, f0, g0, acc);
        idx = nxt;
    }

    // residual: y = x + agg
    const float4* xp = reinterpret_cast<const float4*>(x + (size_t)n * CC);
    float4* yp = reinterpret_cast<float4*>(y + (size_t)n * CC);
#pragma unroll
    for (int q = 0; q < 5; ++q) {
        float4 t = xp[q];
        yp[q] = make_float4(t.x + acc[4*q+0], t.y + acc[4*q+1],
                            t.z + acc[4*q+2], t.w + acc[4*q+3]);
    }
}

// ---------------- BN stats: grid-stride, block-level reduction ----------------
#define STAT_BLOCKS 128
__global__ __launch_bounds__(256) void k_bnstats(const float* __restrict__ y,
                                                 float* __restrict__ sums)
{
    __shared__ float ls[4][2 * CC];
    float s0[CC], s1[CC];
#pragma unroll
    for (int c = 0; c < CC; ++c) { s0[c] = 0.0f; s1[c] = 0.0f; }
    for (int n = blockIdx.x * 256 + threadIdx.x; n < NN; n += STAT_BLOCKS * 256) {
        const float4* p = reinterpret_cast<const float4*>(y + (size_t)n * CC);
#pragma unroll
        for (int q = 0; q < 5; ++q) {
            float4 t = p[q];
            float v0 = t.x, v1 = t.y, v2 = t.z, v3 = t.w;
            s0[4*q+0] += v0; s1[4*q+0] += v0 * v0;
            s0[4*q+1] += v1; s1[4*q+1] += v1 * v1;
            s0[4*q+2] += v2; s1[4*q+2] += v2 * v2;
            s0[4*q+3] += v3; s1[4*q+3] += v3 * v3;
        }
    }
    int lane = threadIdx.x & 63;
    int wave = threadIdx.x >> 6;
#pragma unroll
    for (int c = 0; c < CC; ++c) {
        float a = s0[c], b = s1[c];
        for (int o = 32; o > 0; o >>= 1) {
            a += __shfl_down(a, o);
            b += __shfl_down(b, o);
        }
        if (lane == 0) { ls[wave][c] = a; ls[wave][CC + c] = b; }
    }
    __syncthreads();
    if (threadIdx.x < 2 * CC) {
        float tot = ls[0][threadIdx.x] + ls[1][threadIdx.x] +
                    ls[2][threadIdx.x] + ls[3][threadIdx.x];
        atomicAdd(&sums[threadIdx.x], tot);
    }
}

// ---------------- BN apply + tanh (in place) ----------------
__global__ __launch_bounds__(256) void k_bnapply(float* __restrict__ y,
                                                 const float* __restrict__ sums,
                                                 const float* __restrict__ gam,
                                                 const float* __restrict__ bet)
{
    int n = blockIdx.x * 256 + threadIdx.x;
    if (n >= NN) return;
    const float inv = 1.0f / (float)NN;
    float4* p = reinterpret_cast<float4*>(y + (size_t)n * CC);
    float v[CC];
#pragma unroll
    for (int q = 0; q < 5; ++q) {
        float4 t = p[q];
        v[4*q+0] = t.x; v[4*q+1] = t.y; v[4*q+2] = t.z; v[4*q+3] = t.w;
    }
#pragma unroll
    for (int c = 0; c < CC; ++c) {
        float mean = sums[c] * inv;
        float var  = sums[CC + c] * inv - mean * mean;
        float scale = gam[c] * rsqrtf(var + EPSV);
        float shift = bet[c] - mean * scale;
        v[c] = tanhf(fmaf(v[c], scale, shift));
    }
#pragma unroll
    for (int q = 0; q < 5; ++q) {
        p[q] = make_float4(v[4*q+0], v[4*q+1], v[4*q+2], v[4*q+3]);
    }
}

// ---------------- global add pool ----------------
__global__ __launch_bounds__(256) void k_pool(const float* __restrict__ x,
                                              const int* __restrict__ batch,
                                              float* __restrict__ pooled)
{
    int n = blockIdx.x * 256 + threadIdx.x;
    int nc = n < NN ? n : NN - 1;
    bool valid = n < NN;
    int g = batch[nc];
    float v[CC];
    {
        const float4* p = reinterpret_cast<const float4*>(x + (size_t)nc * CC);
#pragma unroll
        for (int q = 0; q < 5; ++q) {
            float4 t = p[q];
            v[4*q+0] = t.x; v[4*q+1] = t.y; v[4*q+2] = t.z; v[4*q+3] = t.w;
        }
        if (!valid) {
#pragma unroll
            for (int c = 0; c < CC; ++c) v[c] = 0.0f;
        }
    }
    int lane = threadIdx.x & 63;
    int g0 = __shfl(g, 0);
    if (__all(g == g0)) {
#pragma unroll
        for (int c = 0; c < CC; ++c) {
            float a = v[c];
            for (int o = 32; o > 0; o >>= 1) a += __shfl_down(a, o);
            if (lane == 0) atomicAdd(&pooled[(size_t)g0 * CC + c], a);
        }
    } else if (valid) {
#pragma unroll
        for (int c = 0; c < CC; ++c) atomicAdd(&pooled[(size_t)g * CC + c], v[c]);
    }
}

// ---------------- final MLP ----------------
__global__ __launch_bounds__(256) void k_mlp(const float* __restrict__ pooled,
    const float* __restrict__ w1, const float* __restrict__ b1,
    const float* __restrict__ w2, const float* __restrict__ b2,
    const float* __restrict__ w3, const float* __restrict__ b3,
    float* __restrict__ out)
{
    __shared__ float sw1[CC * 32];
    __shared__ float sb1[32];
    __shared__ float sw2[32 * 8];
    __shared__ float sb2[8];
    __shared__ float sw3[8];
    for (int i = threadIdx.x; i < CC * 32; i += 256) sw1[i] = w1[i];
    if (threadIdx.x < 32) sb1[threadIdx.x] = b1[threadIdx.x];
    for (int i = threadIdx.x; i < 32 * 8; i += 256) sw2[i] = w2[i];
    if (threadIdx.x < 8) { sb2[threadIdx.x] = b2[threadIdx.x]; sw3[threadIdx.x] = w3[threadIdx.x]; }
    __syncthreads();

    int gi = blockIdx.x * 256 + threadIdx.x;
    if (gi >= GG) return;

    float p[CC];
    const float4* pp = reinterpret_cast<const float4*>(pooled + (size_t)gi * CC);
#pragma unroll
    for (int q = 0; q < 5; ++q) {
        float4 t = pp[q];
        p[4*q+0] = t.x; p[4*q+1] = t.y; p[4*q+2] = t.z; p[4*q+3] = t.w;
    }
    float h1[32];
#pragma unroll
    for (int j = 0; j < 32; ++j) h1[j] = sb1[j];
#pragma unroll
    for (int c = 0; c < CC; ++c) {
        float pc = p[c];
#pragma unroll
        for (int j = 0; j < 32; ++j) h1[j] = fmaf(pc, sw1[c*32 + j], h1[j]);
    }
#pragma unroll
    for (int j = 0; j < 32; ++j) h1[j] = tanhf(h1[j]);
    float h2[8];
#pragma unroll
    for (int j = 0; j < 8; ++j) h2[j] = sb2[j];
#pragma unroll
    for (int c = 0; c < 32; ++c) {
        float hc = h1[c];
#pragma unroll
        for (int j = 0; j < 8; ++j) h2[j] = fmaf(hc, sw2[c*8 + j], h2[j]);
    }
    float o = b3[0];
#pragma unroll
    for (int j = 0; j < 8; ++j) o = fmaf(tanhf(h2[j]), sw3[j], o);
    out[gi] = o;
}

extern "C" void kernel_launch(void* const* d_in, const int* in_sizes, int n_in,
                              void* d_out, int out_size, void* d_ws, size_t ws_size,
                              hipStream_t stream) {
    const float* x   = (const float*)d_in[0];
    const int*   ei  = (const int*)d_in[1];
    const float* ea  = (const float*)d_in[2];
    const int*   bat = (const int*)d_in[3];
    const float* lfw = (const float*)d_in[4];
    const float* lfb = (const float*)d_in[5];
    const float* lsw = (const float*)d_in[6];
    const float* lsb = (const float*)d_in[7];
    const float* bng = (const float*)d_in[8];
    const float* bnb = (const float*)d_in[9];
    const float* w1  = (const float*)d_in[10];
    const float* b1  = (const float*)d_in[11];
    const float* w2  = (const float*)d_in[12];
    const float* b2  = (const float*)d_in[13];
    const float* w3  = (const float*)d_in[14];
    const float* b3  = (const float*)d_in[15];
    float* out = (float*)d_out;

    char* ws = (char*)d_ws;
    float* A      = (float*)ws;                        // NN*CC floats (8 MB)
    float* B      = A + (size_t)NN * CC;               // NN*CC floats (8 MB)
    int*   cnt    = (int*)(B + (size_t)NN * CC);       // NN ints
    int*   offs   = cnt + NN;                          // NPAD ints
    int*   bsum   = offs + NPAD;                       // 256 ints
    int*   elist  = bsum + 256;                        // EE ints
    float* sums   = (float*)(elist + EE);              // 2*CC floats
    float* pooled = sums + 2 * CC;                     // GG*CC floats

    // ---- CSR build (once; reused by both layers) ----
    hipMemsetAsync(cnt, 0, NN * sizeof(int), stream);
    k_hist<<<(EE + 255) / 256, 256, 0, stream>>>(ei, cnt);
    k_scan_a<<<NB, SCAN_TPB, 0, stream>>>(cnt, offs, bsum);
    k_scan_b<<<1, SCAN_TPB, 0, stream>>>(bsum);
    k_scan_c<<<NPAD / 256, 256, 0, stream>>>(offs, bsum);
    hipMemsetAsync(cnt, 0, NN * sizeof(int), stream);  // reuse as cursor
    k_fill<<<(EE + 255) / 256, 256, 0, stream>>>(ei, offs, cnt, elist);

    const float* xcur = x;
    for (int l = 0; l < LL; ++l) {
        float* y = (l == 0) ? A : B;
        k_agg<<<(NN + 255) / 256, 256, 0, stream>>>(
            xcur, ei, ea, offs, elist,
            lfw + (size_t)l * KK * CC, lfb + (size_t)l * CC,
            lsw + (size_t)l * KK * CC, lsb + (size_t)l * CC, y);
        hipMemsetAsync(sums, 0, 2 * CC * sizeof(float), stream);
        k_bnstats<<<STAT_BLOCKS, 256, 0, stream>>>(y, sums);
        k_bnapply<<<(NN + 255) / 256, 256, 0, stream>>>(y, sums,
            bng + (size_t)l * CC, bnb + (size_t)l * CC);
        xcur = y;
    }
    hipMemsetAsync(pooled, 0, (size_t)GG * CC * sizeof(float), stream);
    k_pool<<<(NN + 255) / 256, 256, 0, stream>>>(xcur, bat, pooled);
    k_mlp<<<(GG + 255) / 256, 256, 0, stream>>>(pooled, w1, b1, w2, b2, w3, b3, out);
}

// Round 3
// 1300.466 us; speedup vs baseline: 3.4970x; 3.4970x over previous
//
#include <hip/hip_runtime.h>
#include <math.h>

#define NN 100000
#define EE 1600000
#define CC 20
#define DD 8
#define GG 1024
#define LL 2
#define KK (2*CC+DD)   // 48
#define EPSV 1e-5f

#define SCAN_TPB 256
#define SCAN_ELEMS 4
#define NB 98                      // ceil(NN / 1024)
#define NPAD (NB * SCAN_TPB * SCAN_ELEMS)  // 100352

// ---------------- CSR build ----------------
__global__ __launch_bounds__(256) void k_hist(const int* __restrict__ ei,
                                              int* __restrict__ cnt) {
    int e = blockIdx.x * 256 + threadIdx.x;
    if (e >= EE) return;
    atomicAdd(&cnt[ei[EE + e]], 1);
}

__global__ __launch_bounds__(SCAN_TPB) void k_scan_a(const int* __restrict__ cnt,
                                                     int* __restrict__ offs,
                                                     int* __restrict__ bsum) {
    __shared__ int sdata[SCAN_TPB];
    int base = blockIdx.x * (SCAN_TPB * SCAN_ELEMS) + threadIdx.x * SCAN_ELEMS;
    int v[SCAN_ELEMS];
    int tot = 0;
#pragma unroll
    for (int i = 0; i < SCAN_ELEMS; ++i) {
        int idx = base + i;
        v[i] = (idx < NN) ? cnt[idx] : 0;
        tot += v[i];
    }
    sdata[threadIdx.x] = tot;
    __syncthreads();
    for (int o = 1; o < SCAN_TPB; o <<= 1) {
        int t = (threadIdx.x >= o) ? sdata[threadIdx.x - o] : 0;
        __syncthreads();
        sdata[threadIdx.x] += t;
        __syncthreads();
    }
    int run = sdata[threadIdx.x] - tot;  // exclusive prefix of this thread
#pragma unroll
    for (int i = 0; i < SCAN_ELEMS; ++i) {
        offs[base + i] = run;
        run += v[i];
    }
    if (threadIdx.x == SCAN_TPB - 1) bsum[blockIdx.x] = sdata[threadIdx.x];
}

__global__ __launch_bounds__(SCAN_TPB) void k_scan_b(int* __restrict__ bsum) {
    __shared__ int s[SCAN_TPB];
    int v = (threadIdx.x < NB) ? bsum[threadIdx.x] : 0;
    s[threadIdx.x] = v;
    __syncthreads();
    for (int o = 1; o < SCAN_TPB; o <<= 1) {
        int t = (threadIdx.x >= o) ? s[threadIdx.x - o] : 0;
        __syncthreads();
        s[threadIdx.x] += t;
        __syncthreads();
    }
    if (threadIdx.x < NB) bsum[threadIdx.x] = s[threadIdx.x] - v;  // exclusive
}

__global__ __launch_bounds__(256) void k_scan_c(int* __restrict__ offs,
                                                const int* __restrict__ bsum) {
    int i = blockIdx.x * 256 + threadIdx.x;   // grid = NPAD/256 exactly
    offs[i] += bsum[i >> 10];
}

__global__ __launch_bounds__(256) void k_fill(const int* __restrict__ ei,
                                              const int* __restrict__ offs,
                                              int* __restrict__ cur,
                                              int* __restrict__ elist) {
    int e = blockIdx.x * 256 + threadIdx.x;
    if (e >= EE) return;
    int d = ei[EE + e];
    int pos = atomicAdd(&cur[d], 1);
    elist[offs[d] + pos] = e;
}

// ---------------- per-node x_i part of both linear maps ----------------
// F0/G0[n] = bias + x[n] @ W[0:CC]  (rows 0..CC-1 of the 48x20 weight)
__global__ __launch_bounds__(256) void k_pre(
    const float* __restrict__ x,
    const float* __restrict__ wf, const float* __restrict__ bf,
    const float* __restrict__ wsm, const float* __restrict__ bs,
    float* __restrict__ F0, float* __restrict__ G0)
{
    int n = blockIdx.x * 256 + threadIdx.x;
    if (n >= NN) return;
    float xn[CC];
    const float4* xp = reinterpret_cast<const float4*>(x + (size_t)n * CC);
#pragma unroll
    for (int q = 0; q < 5; ++q) {
        float4 t = xp[q];
        xn[4*q+0] = t.x; xn[4*q+1] = t.y; xn[4*q+2] = t.z; xn[4*q+3] = t.w;
    }
    float f[CC], g[CC];
#pragma unroll
    for (int c = 0; c < CC; ++c) { f[c] = bf[c]; g[c] = bs[c]; }
#pragma unroll
    for (int k = 0; k < CC; ++k) {
        float zk = xn[k];
#pragma unroll
        for (int c = 0; c < CC; ++c) {
            f[c] = fmaf(zk, wf[k*CC + c], f[c]);
            g[c] = fmaf(zk, wsm[k*CC + c], g[c]);
        }
    }
    float4* fp = reinterpret_cast<float4*>(F0 + (size_t)n * CC);
    float4* gp = reinterpret_cast<float4*>(G0 + (size_t)n * CC);
#pragma unroll
    for (int q = 0; q < 5; ++q) {
        fp[q] = make_float4(f[4*q+0], f[4*q+1], f[4*q+2], f[4*q+3]);
        gp[q] = make_float4(g[4*q+0], g[4*q+1], g[4*q+2], g[4*q+3]);
    }
}

// ---------------- fused edge-message + aggregate + residual ----------------
// One thread per node. Weights read from global with wave-uniform indices
// (compiler scalarizes -> s_load, SGPR operand in v_fma). z streamed from
// global straight into FMAs: no z array, no double buffer -> no spills.
__global__ __launch_bounds__(256, 3) void k_agg(
    const float* __restrict__ x, const int* __restrict__ ei,
    const float* __restrict__ ea,
    const int* __restrict__ offs, const int* __restrict__ elist,
    const float* __restrict__ wf, const float* __restrict__ wsm,
    const float* __restrict__ F0, const float* __restrict__ G0,
    float* __restrict__ y)
{
    int n = blockIdx.x * 256 + threadIdx.x;
    if (n >= NN) return;

    float f0[CC], g0[CC];
    {
        const float4* fp = reinterpret_cast<const float4*>(F0 + (size_t)n * CC);
        const float4* gp = reinterpret_cast<const float4*>(G0 + (size_t)n * CC);
#pragma unroll
        for (int q = 0; q < 5; ++q) {
            float4 a = fp[q], b = gp[q];
            f0[4*q+0] = a.x; f0[4*q+1] = a.y; f0[4*q+2] = a.z; f0[4*q+3] = a.w;
            g0[4*q+0] = b.x; g0[4*q+1] = b.y; g0[4*q+2] = b.z; g0[4*q+3] = b.w;
        }
    }

    float acc[CC];
#pragma unroll
    for (int c = 0; c < CC; ++c) acc[c] = 0.0f;

    int beg = offs[n];
    int end = offs[n + 1];

#pragma unroll 1
    for (int i = beg; i < end; ++i) {
        int e = elist[i];
        int s = ei[e];
        const float4* xp = reinterpret_cast<const float4*>(x + (size_t)s * CC);
        const float4* ep = reinterpret_cast<const float4*>(ea + (size_t)e * DD);

        float f[CC], g[CC];
#pragma unroll
        for (int c = 0; c < CC; ++c) { f[c] = f0[c]; g[c] = g0[c]; }

        // x_j part: weight rows CC .. 2CC-1
#pragma unroll
        for (int q = 0; q < 5; ++q) {
            float4 v = xp[q];
            float zv[4] = {v.x, v.y, v.z, v.w};
#pragma unroll
            for (int j = 0; j < 4; ++j) {
                int row = (CC + 4*q + j) * CC;
                float zk = zv[j];
#pragma unroll
                for (int c = 0; c < CC; ++c) {
                    f[c] = fmaf(zk, wf[row + c], f[c]);
                    g[c] = fmaf(zk, wsm[row + c], g[c]);
                }
            }
        }
        // edge-attr part: weight rows 2CC .. KK-1
#pragma unroll
        for (int q = 0; q < 2; ++q) {
            float4 v = ep[q];
            float zv[4] = {v.x, v.y, v.z, v.w};
#pragma unroll
            for (int j = 0; j < 4; ++j) {
                int row = (2*CC + 4*q + j) * CC;
                float zk = zv[j];
#pragma unroll
                for (int c = 0; c < CC; ++c) {
                    f[c] = fmaf(zk, wf[row + c], f[c]);
                    g[c] = fmaf(zk, wsm[row + c], g[c]);
                }
            }
        }
#pragma unroll
        for (int c = 0; c < CC; ++c) {
            float sg = 1.0f / (1.0f + __expf(-f[c]));
            float a = fabsf(g[c]);
            float sp = fmaxf(g[c], 0.0f) + __logf(1.0f + __expf(-a));
            acc[c] += sg * sp;
        }
    }

    // residual: y = x + agg
    const float4* xp = reinterpret_cast<const float4*>(x + (size_t)n * CC);
    float4* yp = reinterpret_cast<float4*>(y + (size_t)n * CC);
#pragma unroll
    for (int q = 0; q < 5; ++q) {
        float4 t = xp[q];
        yp[q] = make_float4(t.x + acc[4*q+0], t.y + acc[4*q+1],
                            t.z + acc[4*q+2], t.w + acc[4*q+3]);
    }
}

// ---------------- BN stats: grid-stride, block-level reduction ----------------
#define STAT_BLOCKS 128
__global__ __launch_bounds__(256) void k_bnstats(const float* __restrict__ y,
                                                 float* __restrict__ sums)
{
    __shared__ float ls[4][2 * CC];
    float s0[CC], s1[CC];
#pragma unroll
    for (int c = 0; c < CC; ++c) { s0[c] = 0.0f; s1[c] = 0.0f; }
    for (int n = blockIdx.x * 256 + threadIdx.x; n < NN; n += STAT_BLOCKS * 256) {
        const float4* p = reinterpret_cast<const float4*>(y + (size_t)n * CC);
#pragma unroll
        for (int q = 0; q < 5; ++q) {
            float4 t = p[q];
            float v0 = t.x, v1 = t.y, v2 = t.z, v3 = t.w;
            s0[4*q+0] += v0; s1[4*q+0] += v0 * v0;
            s0[4*q+1] += v1; s1[4*q+1] += v1 * v1;
            s0[4*q+2] += v2; s1[4*q+2] += v2 * v2;
            s0[4*q+3] += v3; s1[4*q+3] += v3 * v3;
        }
    }
    int lane = threadIdx.x & 63;
    int wave = threadIdx.x >> 6;
#pragma unroll
    for (int c = 0; c < CC; ++c) {
        float a = s0[c], b = s1[c];
        for (int o = 32; o > 0; o >>= 1) {
            a += __shfl_down(a, o);
            b += __shfl_down(b, o);
        }
        if (lane == 0) { ls[wave][c] = a; ls[wave][CC + c] = b; }
    }
    __syncthreads();
    if (threadIdx.x < 2 * CC) {
        float tot = ls[0][threadIdx.x] + ls[1][threadIdx.x] +
                    ls[2][threadIdx.x] + ls[3][threadIdx.x];
        atomicAdd(&sums[threadIdx.x], tot);
    }
}

// ---------------- BN apply + tanh (in place) ----------------
__global__ __launch_bounds__(256) void k_bnapply(float* __restrict__ y,
                                                 const float* __restrict__ sums,
                                                 const float* __restrict__ gam,
                                                 const float* __restrict__ bet)
{
    int n = blockIdx.x * 256 + threadIdx.x;
    if (n >= NN) return;
    const float inv = 1.0f / (float)NN;
    float4* p = reinterpret_cast<float4*>(y + (size_t)n * CC);
    float v[CC];
#pragma unroll
    for (int q = 0; q < 5; ++q) {
        float4 t = p[q];
        v[4*q+0] = t.x; v[4*q+1] = t.y; v[4*q+2] = t.z; v[4*q+3] = t.w;
    }
#pragma unroll
    for (int c = 0; c < CC; ++c) {
        float mean = sums[c] * inv;
        float var  = sums[CC + c] * inv - mean * mean;
        float scale = gam[c] * rsqrtf(var + EPSV);
        float shift = bet[c] - mean * scale;
        v[c] = tanhf(fmaf(v[c], scale, shift));
    }
#pragma unroll
    for (int q = 0; q < 5; ++q) {
        p[q] = make_float4(v[4*q+0], v[4*q+1], v[4*q+2], v[4*q+3]);
    }
}

// ---------------- global add pool ----------------
__global__ __launch_bounds__(256) void k_pool(const float* __restrict__ x,
                                              const int* __restrict__ batch,
                                              float* __restrict__ pooled)
{
    int n = blockIdx.x * 256 + threadIdx.x;
    int nc = n < NN ? n : NN - 1;
    bool valid = n < NN;
    int g = batch[nc];
    float v[CC];
    {
        const float4* p = reinterpret_cast<const float4*>(x + (size_t)nc * CC);
#pragma unroll
        for (int q = 0; q < 5; ++q) {
            float4 t = p[q];
            v[4*q+0] = t.x; v[4*q+1] = t.y; v[4*q+2] = t.z; v[4*q+3] = t.w;
        }
        if (!valid) {
#pragma unroll
            for (int c = 0; c < CC; ++c) v[c] = 0.0f;
        }
    }
    int lane = threadIdx.x & 63;
    int g0 = __shfl(g, 0);
    if (__all(g == g0)) {
#pragma unroll
        for (int c = 0; c < CC; ++c) {
            float a = v[c];
            for (int o = 32; o > 0; o >>= 1) a += __shfl_down(a, o);
            if (lane == 0) atomicAdd(&pooled[(size_t)g0 * CC + c], a);
        }
    } else if (valid) {
#pragma unroll
        for (int c = 0; c < CC; ++c) atomicAdd(&pooled[(size_t)g * CC + c], v[c]);
    }
}

// ---------------- final MLP ----------------
__global__ __launch_bounds__(256) void k_mlp(const float* __restrict__ pooled,
    const float* __restrict__ w1, const float* __restrict__ b1,
    const float* __restrict__ w2, const float* __restrict__ b2,
    const float* __restrict__ w3, const float* __restrict__ b3,
    float* __restrict__ out)
{
    int gi = blockIdx.x * 256 + threadIdx.x;
    if (gi >= GG) return;

    float p[CC];
    const float4* pp = reinterpret_cast<const float4*>(pooled + (size_t)gi * CC);
#pragma unroll
    for (int q = 0; q < 5; ++q) {
        float4 t = pp[q];
        p[4*q+0] = t.x; p[4*q+1] = t.y; p[4*q+2] = t.z; p[4*q+3] = t.w;
    }
    float h1[32];
#pragma unroll
    for (int j = 0; j < 32; ++j) h1[j] = b1[j];
#pragma unroll
    for (int c = 0; c < CC; ++c) {
        float pc = p[c];
#pragma unroll
        for (int j = 0; j < 32; ++j) h1[j] = fmaf(pc, w1[c*32 + j], h1[j]);
    }
#pragma unroll
    for (int j = 0; j < 32; ++j) h1[j] = tanhf(h1[j]);
    float h2[8];
#pragma unroll
    for (int j = 0; j < 8; ++j) h2[j] = b2[j];
#pragma unroll
    for (int c = 0; c < 32; ++c) {
        float hc = h1[c];
#pragma unroll
        for (int j = 0; j < 8; ++j) h2[j] = fmaf(hc, w2[c*8 + j], h2[j]);
    }
    float o = b3[0];
#pragma unroll
    for (int j = 0; j < 8; ++j) o = fmaf(tanhf(h2[j]), w3[j], o);
    out[gi] = o;
}

extern "C" void kernel_launch(void* const* d_in, const int* in_sizes, int n_in,
                              void* d_out, int out_size, void* d_ws, size_t ws_size,
                              hipStream_t stream) {
    const float* x   = (const float*)d_in[0];
    const int*   ei  = (const int*)d_in[1];
    const float* ea  = (const float*)d_in[2];
    const int*   bat = (const int*)d_in[3];
    const float* lfw = (const float*)d_in[4];
    const float* lfb = (const float*)d_in[5];
    const float* lsw = (const float*)d_in[6];
    const float* lsb = (const float*)d_in[7];
    const float* bng = (const float*)d_in[8];
    const float* bnb = (const float*)d_in[9];
    const float* w1  = (const float*)d_in[10];
    const float* b1  = (const float*)d_in[11];
    const float* w2  = (const float*)d_in[12];
    const float* b2  = (const float*)d_in[13];
    const float* w3  = (const float*)d_in[14];
    const float* b3  = (const float*)d_in[15];
    float* out = (float*)d_out;

    char* ws = (char*)d_ws;
    float* A      = (float*)ws;                        // NN*CC floats (8 MB)
    float* B      = A + (size_t)NN * CC;               // NN*CC floats (8 MB)
    float* F0     = B + (size_t)NN * CC;               // NN*CC floats (8 MB)
    float* G0     = F0 + (size_t)NN * CC;              // NN*CC floats (8 MB)
    int*   cnt    = (int*)(G0 + (size_t)NN * CC);      // NN ints
    int*   offs   = cnt + NN;                          // NPAD ints
    int*   bsum   = offs + NPAD;                       // 256 ints
    int*   elist  = bsum + 256;                        // EE ints
    float* sums   = (float*)(elist + EE);              // 2*CC floats
    float* pooled = sums + 2 * CC;                     // GG*CC floats

    // ---- CSR build (once; reused by both layers) ----
    hipMemsetAsync(cnt, 0, NN * sizeof(int), stream);
    k_hist<<<(EE + 255) / 256, 256, 0, stream>>>(ei, cnt);
    k_scan_a<<<NB, SCAN_TPB, 0, stream>>>(cnt, offs, bsum);
    k_scan_b<<<1, SCAN_TPB, 0, stream>>>(bsum);
    k_scan_c<<<NPAD / 256, 256, 0, stream>>>(offs, bsum);
    hipMemsetAsync(cnt, 0, NN * sizeof(int), stream);  // reuse as cursor
    k_fill<<<(EE + 255) / 256, 256, 0, stream>>>(ei, offs, cnt, elist);

    const int nblocks = (NN + 255) / 256;
    const float* xcur = x;
    for (int l = 0; l < LL; ++l) {
        float* y = (l == 0) ? A : B;
        const float* wfl = lfw + (size_t)l * KK * CC;
        const float* wsl = lsw + (size_t)l * KK * CC;
        k_pre<<<nblocks, 256, 0, stream>>>(
            xcur, wfl, lfb + (size_t)l * CC, wsl, lsb + (size_t)l * CC, F0, G0);
        k_agg<<<nblocks, 256, 0, stream>>>(
            xcur, ei, ea, offs, elist, wfl, wsl, F0, G0, y);
        hipMemsetAsync(sums, 0, 2 * CC * sizeof(float), stream);
        k_bnstats<<<STAT_BLOCKS, 256, 0, stream>>>(y, sums);
        k_bnapply<<<nblocks, 256, 0, stream>>>(y, sums,
            bng + (size_t)l * CC, bnb + (size_t)l * CC);
        xcur = y;
    }
    hipMemsetAsync(pooled, 0, (size_t)GG * CC * sizeof(float), stream);
    k_pool<<<nblocks, 256, 0, stream>>>(xcur, bat, pooled);
    k_mlp<<<(GG + 255) / 256, 256, 0, stream>>>(pooled, w1, b1, w2, b2, w3, b3, out);
}

// Round 4
// 741.132 us; speedup vs baseline: 6.1362x; 1.7547x over previous
//
#include <hip/hip_runtime.h>
#include <math.h>

#define NN 100000
#define EE 1600000
#define CC 20
#define DD 8
#define GG 1024
#define LL 2
#define KK (2*CC+DD)   // 48
#define EPSV 1e-5f

#define SCAN_TPB 256
#define SCAN_ELEMS 4
#define NB 98                      // ceil(NN / 1024)
#define NPAD (NB * SCAN_TPB * SCAN_ELEMS)  // 100352

// ---------------- CSR build ----------------
__global__ __launch_bounds__(256) void k_hist(const int* __restrict__ ei,
                                              int* __restrict__ cnt) {
    int e = blockIdx.x * 256 + threadIdx.x;
    if (e >= EE) return;
    atomicAdd(&cnt[ei[EE + e]], 1);
}

__global__ __launch_bounds__(SCAN_TPB) void k_scan_a(const int* __restrict__ cnt,
                                                     int* __restrict__ offs,
                                                     int* __restrict__ bsum) {
    __shared__ int sdata[SCAN_TPB];
    int base = blockIdx.x * (SCAN_TPB * SCAN_ELEMS) + threadIdx.x * SCAN_ELEMS;
    int v[SCAN_ELEMS];
    int tot = 0;
#pragma unroll
    for (int i = 0; i < SCAN_ELEMS; ++i) {
        int idx = base + i;
        v[i] = (idx < NN) ? cnt[idx] : 0;
        tot += v[i];
    }
    sdata[threadIdx.x] = tot;
    __syncthreads();
    for (int o = 1; o < SCAN_TPB; o <<= 1) {
        int t = (threadIdx.x >= o) ? sdata[threadIdx.x - o] : 0;
        __syncthreads();
        sdata[threadIdx.x] += t;
        __syncthreads();
    }
    int run = sdata[threadIdx.x] - tot;  // exclusive prefix of this thread
#pragma unroll
    for (int i = 0; i < SCAN_ELEMS; ++i) {
        offs[base + i] = run;
        run += v[i];
    }
    if (threadIdx.x == SCAN_TPB - 1) bsum[blockIdx.x] = sdata[threadIdx.x];
}

__global__ __launch_bounds__(SCAN_TPB) void k_scan_b(int* __restrict__ bsum) {
    __shared__ int s[SCAN_TPB];
    int v = (threadIdx.x < NB) ? bsum[threadIdx.x] : 0;
    s[threadIdx.x] = v;
    __syncthreads();
    for (int o = 1; o < SCAN_TPB; o <<= 1) {
        int t = (threadIdx.x >= o) ? s[threadIdx.x - o] : 0;
        __syncthreads();
        s[threadIdx.x] += t;
        __syncthreads();
    }
    if (threadIdx.x < NB) bsum[threadIdx.x] = s[threadIdx.x] - v;  // exclusive
}

__global__ __launch_bounds__(256) void k_scan_c(int* __restrict__ offs,
                                                const int* __restrict__ bsum) {
    int i = blockIdx.x * 256 + threadIdx.x;   // grid = NPAD/256 exactly
    offs[i] += bsum[i >> 10];
}

__global__ __launch_bounds__(256) void k_fill(const int* __restrict__ ei,
                                              const int* __restrict__ offs,
                                              int* __restrict__ cur,
                                              int* __restrict__ elist) {
    int e = blockIdx.x * 256 + threadIdx.x;
    if (e >= EE) return;
    int d = ei[EE + e];
    int pos = atomicAdd(&cur[d], 1);
    elist[offs[d] + pos] = e;
}

// ---------------- per-node precompute: P0 = [bf + x@Wf[0:20] | bs + x@Ws[0:20]]
//                  PX = [x@Wf[20:40] | x@Ws[20:40]] ; y := x (residual init)
__global__ __launch_bounds__(256) void k_pre0(
    const float* __restrict__ x,
    const float* __restrict__ wf, const float* __restrict__ bf,
    const float* __restrict__ wsm, const float* __restrict__ bs,
    float* __restrict__ P0, float* __restrict__ PX, float* __restrict__ y)
{
    int n = blockIdx.x * 256 + threadIdx.x;
    if (n >= NN) return;
    float xn[CC];
    const float4* xp = reinterpret_cast<const float4*>(x + (size_t)n * CC);
    float4* yp = reinterpret_cast<float4*>(y + (size_t)n * CC);
#pragma unroll
    for (int q = 0; q < 5; ++q) {
        float4 t = xp[q];
        yp[q] = t;
        xn[4*q+0] = t.x; xn[4*q+1] = t.y; xn[4*q+2] = t.z; xn[4*q+3] = t.w;
    }
    float f0[CC], g0[CC], fx[CC], gx[CC];
#pragma unroll
    for (int c = 0; c < CC; ++c) { f0[c] = bf[c]; g0[c] = bs[c]; fx[c] = 0.f; gx[c] = 0.f; }
#pragma unroll
    for (int k = 0; k < CC; ++k) {
        float zk = xn[k];
#pragma unroll
        for (int c = 0; c < CC; ++c) {
            f0[c] = fmaf(zk, wf[k*CC + c], f0[c]);
            g0[c] = fmaf(zk, wsm[k*CC + c], g0[c]);
            fx[c] = fmaf(zk, wf[(CC+k)*CC + c], fx[c]);
            gx[c] = fmaf(zk, wsm[(CC+k)*CC + c], gx[c]);
        }
    }
    float4* pp = reinterpret_cast<float4*>(P0 + (size_t)n * 2*CC);
    float4* px = reinterpret_cast<float4*>(PX + (size_t)n * 2*CC);
#pragma unroll
    for (int q = 0; q < 5; ++q) {
        pp[q]   = make_float4(f0[4*q+0], f0[4*q+1], f0[4*q+2], f0[4*q+3]);
        pp[5+q] = make_float4(g0[4*q+0], g0[4*q+1], g0[4*q+2], g0[4*q+3]);
        px[q]   = make_float4(fx[4*q+0], fx[4*q+1], fx[4*q+2], fx[4*q+3]);
        px[5+q] = make_float4(gx[4*q+0], gx[4*q+1], gx[4*q+2], gx[4*q+3]);
    }
}

// ---------------- BN(prev layer) + tanh in place, then precompute for next layer
__global__ __launch_bounds__(256) void k_bnpre(
    float* __restrict__ y, const float* __restrict__ sums,
    const float* __restrict__ gam, const float* __restrict__ bet,
    const float* __restrict__ wf, const float* __restrict__ bf,
    const float* __restrict__ wsm, const float* __restrict__ bs,
    float* __restrict__ P0, float* __restrict__ PX)
{
    int n = blockIdx.x * 256 + threadIdx.x;
    if (n >= NN) return;
    const float inv = 1.0f / (float)NN;
    float4* yp = reinterpret_cast<float4*>(y + (size_t)n * CC);
    float xn[CC];
#pragma unroll
    for (int q = 0; q < 5; ++q) {
        float4 t = yp[q];
        xn[4*q+0] = t.x; xn[4*q+1] = t.y; xn[4*q+2] = t.z; xn[4*q+3] = t.w;
    }
#pragma unroll
    for (int c = 0; c < CC; ++c) {
        float mean = sums[c] * inv;
        float var  = sums[CC + c] * inv - mean * mean;
        float scale = gam[c] * rsqrtf(var + EPSV);
        float shift = bet[c] - mean * scale;
        xn[c] = tanhf(fmaf(xn[c], scale, shift));
    }
#pragma unroll
    for (int q = 0; q < 5; ++q)
        yp[q] = make_float4(xn[4*q+0], xn[4*q+1], xn[4*q+2], xn[4*q+3]);

    float f0[CC], g0[CC], fx[CC], gx[CC];
#pragma unroll
    for (int c = 0; c < CC; ++c) { f0[c] = bf[c]; g0[c] = bs[c]; fx[c] = 0.f; gx[c] = 0.f; }
#pragma unroll
    for (int k = 0; k < CC; ++k) {
        float zk = xn[k];
#pragma unroll
        for (int c = 0; c < CC; ++c) {
            f0[c] = fmaf(zk, wf[k*CC + c], f0[c]);
            g0[c] = fmaf(zk, wsm[k*CC + c], g0[c]);
            fx[c] = fmaf(zk, wf[(CC+k)*CC + c], fx[c]);
            gx[c] = fmaf(zk, wsm[(CC+k)*CC + c], gx[c]);
        }
    }
    float4* pp = reinterpret_cast<float4*>(P0 + (size_t)n * 2*CC);
    float4* px = reinterpret_cast<float4*>(PX + (size_t)n * 2*CC);
#pragma unroll
    for (int q = 0; q < 5; ++q) {
        pp[q]   = make_float4(f0[4*q+0], f0[4*q+1], f0[4*q+2], f0[4*q+3]);
        pp[5+q] = make_float4(g0[4*q+0], g0[4*q+1], g0[4*q+2], g0[4*q+3]);
        px[q]   = make_float4(fx[4*q+0], fx[4*q+1], fx[4*q+2], fx[4*q+3]);
        px[5+q] = make_float4(gx[4*q+0], gx[4*q+1], gx[4*q+2], gx[4*q+3]);
    }
}

// ---------------- edge message ----------------
__device__ __forceinline__ void edge_msg(int e, int s, int d,
    const float* __restrict__ ea, const float* __restrict__ P0,
    const float* __restrict__ PX,
    const float* __restrict__ wfe, const float* __restrict__ wse,
    float* m)
{
    const float4* eap = reinterpret_cast<const float4*>(ea + (size_t)e * DD);
    float4 ea0 = eap[0], ea1 = eap[1];
    float eaw[8] = {ea0.x, ea0.y, ea0.z, ea0.w, ea1.x, ea1.y, ea1.z, ea1.w};
    const float4* p0 = reinterpret_cast<const float4*>(P0 + (size_t)d * 2*CC);
    const float4* px = reinterpret_cast<const float4*>(PX + (size_t)s * 2*CC);
    float f[CC], g[CC];
#pragma unroll
    for (int q = 0; q < 5; ++q) {
        float4 a = p0[q], b = px[q];
        f[4*q+0] = a.x + b.x; f[4*q+1] = a.y + b.y;
        f[4*q+2] = a.z + b.z; f[4*q+3] = a.w + b.w;
    }
#pragma unroll
    for (int q = 0; q < 5; ++q) {
        float4 a = p0[5+q], b = px[5+q];
        g[4*q+0] = a.x + b.x; g[4*q+1] = a.y + b.y;
        g[4*q+2] = a.z + b.z; g[4*q+3] = a.w + b.w;
    }
#pragma unroll
    for (int k = 0; k < 8; ++k) {
        float zk = eaw[k];
#pragma unroll
        for (int c = 0; c < CC; ++c) {
            f[c] = fmaf(zk, wfe[k*CC + c], f[c]);
            g[c] = fmaf(zk, wse[k*CC + c], g[c]);
        }
    }
#pragma unroll
    for (int c = 0; c < CC; ++c) {
        float sg = 1.0f / (1.0f + __expf(-f[c]));
        float sp = fmaxf(g[c], 0.0f) + __logf(1.0f + __expf(-fabsf(g[c])));
        m[c] = sg * sp;
    }
}

__device__ __forceinline__ void commit(float* __restrict__ y, int d,
                                       const float* acc, bool complete) {
    float* yp = y + (size_t)d * CC;
    if (complete) {
        float4* y4 = reinterpret_cast<float4*>(yp);
#pragma unroll
        for (int q = 0; q < 5; ++q) {
            float4 t = y4[q];
            t.x += acc[4*q+0]; t.y += acc[4*q+1];
            t.z += acc[4*q+2]; t.w += acc[4*q+3];
            y4[q] = t;
        }
    } else {
#pragma unroll
        for (int c = 0; c < CC; ++c) atomicAdd(yp + c, acc[c]);
    }
}

// ---------------- fused edge kernel: 4 sorted edges/thread, wave seg-reduce ----------------
__global__ __launch_bounds__(256, 3) void k_msg(
    const int* __restrict__ ei, const float* __restrict__ ea,
    const int* __restrict__ elist, const int* __restrict__ offs,
    const float* __restrict__ P0, const float* __restrict__ PX,
    const float* __restrict__ wfe, const float* __restrict__ wse,
    float* __restrict__ y)
{
    int t = blockIdx.x * 256 + threadIdx.x;
    int i0 = t * 4;
    if (i0 >= EE) return;               // whole-wave uniform exit (EE/4 % 64 == 0)
    int lane = threadIdx.x & 63;
    int W = i0 & ~255;                  // wave's first sorted-edge index

    int4 ev = reinterpret_cast<const int4*>(elist)[t];
    int e_[4] = {ev.x, ev.y, ev.z, ev.w};
    int s_[4], d_[4];
#pragma unroll
    for (int j = 0; j < 4; ++j) { s_[j] = ei[e_[j]]; d_[j] = ei[EE + e_[j]]; }

    float trail[CC], lead[CC], m[CC];
    int trail_d, lead_d = -1;

    edge_msg(e_[0], s_[0], d_[0], ea, P0, PX, wfe, wse, trail);
    trail_d = d_[0];
#pragma unroll
    for (int j = 1; j < 4; ++j) {
        edge_msg(e_[j], s_[j], d_[j], ea, P0, PX, wfe, wse, m);
        if (d_[j] == trail_d) {
#pragma unroll
            for (int c = 0; c < CC; ++c) trail[c] += m[c];
        } else {
            if (lead_d < 0) {
#pragma unroll
                for (int c = 0; c < CC; ++c) lead[c] = trail[c];
                lead_d = trail_d;
            } else {
                commit(y, trail_d, trail, true);   // run fully inside thread
            }
#pragma unroll
            for (int c = 0; c < CC; ++c) trail[c] = m[c];
            trail_d = d_[j];
        }
    }

    // segmented inclusive scan of trail across lanes (d monotone -> simple pred)
    float mk[6];
#pragma unroll
    for (int k = 0; k < 6; ++k) {
        int off = 1 << k;
        int dfrom = __shfl_up(trail_d, off);
        mk[k] = (lane >= off && dfrom == trail_d) ? 1.0f : 0.0f;
    }
#pragma unroll
    for (int k = 0; k < 6; ++k) {
        int off = 1 << k;
#pragma unroll
        for (int c = 0; c < CC; ++c) {
            float tt = __shfl_up(trail[c], off);
            trail[c] = fmaf(tt, mk[k], trail[c]);
        }
    }
    int dt_next = __shfl_down(trail_d, 1);
    int ld_next = __shfl_down(lead_d, 1);
    // incoming chain for this thread's leading run (from scanned trail of lane-1)
    int d_prev = __shfl_up(trail_d, 1);
    float gate = (lane > 0 && d_prev == lead_d) ? 1.0f : 0.0f;
#pragma unroll
    for (int c = 0; c < CC; ++c) {
        float tt = __shfl_up(trail[c], 1);
        lead[c] = fmaf(tt, gate, lead[c]);
    }

    bool tail = (lane == 63) || (dt_next != trail_d && ld_next != trail_d);
    if (tail) {
        int o0 = offs[trail_d], o1 = offs[trail_d + 1];
        bool complete = (o0 >= W) && (o1 == i0 + 4);
        commit(y, trail_d, trail, complete);
    }
    if (lead_d >= 0) {
        int o0 = offs[lead_d];
        commit(y, lead_d, lead, o0 >= W);   // run ends mid-thread -> within wave
    }
}

// ---------------- BN stats: grid-stride, block-level reduction ----------------
#define STAT_BLOCKS 128
__global__ __launch_bounds__(256) void k_bnstats(const float* __restrict__ y,
                                                 float* __restrict__ sums)
{
    __shared__ float ls[4][2 * CC];
    float s0[CC], s1[CC];
#pragma unroll
    for (int c = 0; c < CC; ++c) { s0[c] = 0.0f; s1[c] = 0.0f; }
    for (int n = blockIdx.x * 256 + threadIdx.x; n < NN; n += STAT_BLOCKS * 256) {
        const float4* p = reinterpret_cast<const float4*>(y + (size_t)n * CC);
#pragma unroll
        for (int q = 0; q < 5; ++q) {
            float4 t = p[q];
            s0[4*q+0] += t.x; s1[4*q+0] += t.x * t.x;
            s0[4*q+1] += t.y; s1[4*q+1] += t.y * t.y;
            s0[4*q+2] += t.z; s1[4*q+2] += t.z * t.z;
            s0[4*q+3] += t.w; s1[4*q+3] += t.w * t.w;
        }
    }
    int lane = threadIdx.x & 63;
    int wave = threadIdx.x >> 6;
#pragma unroll
    for (int c = 0; c < CC; ++c) {
        float a = s0[c], b = s1[c];
        for (int o = 32; o > 0; o >>= 1) {
            a += __shfl_down(a, o);
            b += __shfl_down(b, o);
        }
        if (lane == 0) { ls[wave][c] = a; ls[wave][CC + c] = b; }
    }
    __syncthreads();
    if (threadIdx.x < 2 * CC) {
        float tot = ls[0][threadIdx.x] + ls[1][threadIdx.x] +
                    ls[2][threadIdx.x] + ls[3][threadIdx.x];
        atomicAdd(&sums[threadIdx.x], tot);
    }
}

// ---------------- final: BN + tanh + global_add_pool ----------------
__global__ __launch_bounds__(256) void k_bnpool(
    const float* __restrict__ y, const float* __restrict__ sums,
    const float* __restrict__ gam, const float* __restrict__ bet,
    const int* __restrict__ batch, float* __restrict__ pooled)
{
    int n = blockIdx.x * 256 + threadIdx.x;
    int nc = n < NN ? n : NN - 1;
    bool valid = n < NN;
    int g = batch[nc];
    const float inv = 1.0f / (float)NN;
    float v[CC];
    const float4* p = reinterpret_cast<const float4*>(y + (size_t)nc * CC);
#pragma unroll
    for (int q = 0; q < 5; ++q) {
        float4 t = p[q];
        v[4*q+0] = t.x; v[4*q+1] = t.y; v[4*q+2] = t.z; v[4*q+3] = t.w;
    }
#pragma unroll
    for (int c = 0; c < CC; ++c) {
        float mean = sums[c] * inv;
        float var  = sums[CC + c] * inv - mean * mean;
        float scale = gam[c] * rsqrtf(var + EPSV);
        float shift = bet[c] - mean * scale;
        v[c] = tanhf(fmaf(v[c], scale, shift));
        if (!valid) v[c] = 0.0f;
    }
    int lane = threadIdx.x & 63;
    int g0 = __shfl(g, 0);
    if (__all(g == g0)) {
#pragma unroll
        for (int c = 0; c < CC; ++c) {
            float a = v[c];
            for (int o = 32; o > 0; o >>= 1) a += __shfl_down(a, o);
            if (lane == 0) atomicAdd(&pooled[(size_t)g0 * CC + c], a);
        }
    } else if (valid) {
#pragma unroll
        for (int c = 0; c < CC; ++c) atomicAdd(&pooled[(size_t)g * CC + c], v[c]);
    }
}

// ---------------- final MLP ----------------
__global__ __launch_bounds__(256) void k_mlp(const float* __restrict__ pooled,
    const float* __restrict__ w1, const float* __restrict__ b1,
    const float* __restrict__ w2, const float* __restrict__ b2,
    const float* __restrict__ w3, const float* __restrict__ b3,
    float* __restrict__ out)
{
    int gi = blockIdx.x * 256 + threadIdx.x;
    if (gi >= GG) return;

    float p[CC];
    const float4* pp = reinterpret_cast<const float4*>(pooled + (size_t)gi * CC);
#pragma unroll
    for (int q = 0; q < 5; ++q) {
        float4 t = pp[q];
        p[4*q+0] = t.x; p[4*q+1] = t.y; p[4*q+2] = t.z; p[4*q+3] = t.w;
    }
    float h1[32];
#pragma unroll
    for (int j = 0; j < 32; ++j) h1[j] = b1[j];
#pragma unroll
    for (int c = 0; c < CC; ++c) {
        float pc = p[c];
#pragma unroll
        for (int j = 0; j < 32; ++j) h1[j] = fmaf(pc, w1[c*32 + j], h1[j]);
    }
#pragma unroll
    for (int j = 0; j < 32; ++j) h1[j] = tanhf(h1[j]);
    float h2[8];
#pragma unroll
    for (int j = 0; j < 8; ++j) h2[j] = b2[j];
#pragma unroll
    for (int c = 0; c < 32; ++c) {
        float hc = h1[c];
#pragma unroll
        for (int j = 0; j < 8; ++j) h2[j] = fmaf(hc, w2[c*8 + j], h2[j]);
    }
    float o = b3[0];
#pragma unroll
    for (int j = 0; j < 8; ++j) o = fmaf(tanhf(h2[j]), w3[j], o);
    out[gi] = o;
}

extern "C" void kernel_launch(void* const* d_in, const int* in_sizes, int n_in,
                              void* d_out, int out_size, void* d_ws, size_t ws_size,
                              hipStream_t stream) {
    const float* x   = (const float*)d_in[0];
    const int*   ei  = (const int*)d_in[1];
    const float* ea  = (const float*)d_in[2];
    const int*   bat = (const int*)d_in[3];
    const float* lfw = (const float*)d_in[4];
    const float* lfb = (const float*)d_in[5];
    const float* lsw = (const float*)d_in[6];
    const float* lsb = (const float*)d_in[7];
    const float* bng = (const float*)d_in[8];
    const float* bnb = (const float*)d_in[9];
    const float* w1  = (const float*)d_in[10];
    const float* b1  = (const float*)d_in[11];
    const float* w2  = (const float*)d_in[12];
    const float* b2  = (const float*)d_in[13];
    const float* w3  = (const float*)d_in[14];
    const float* b3  = (const float*)d_in[15];
    float* out = (float*)d_out;

    char* ws = (char*)d_ws;
    float* y      = (float*)ws;                        // NN*20 f      (8 MB)
    float* P0     = y + (size_t)NN * CC;               // NN*40 f      (16 MB)
    float* PX     = P0 + (size_t)NN * 2 * CC;          // NN*40 f      (16 MB)
    int*   elist  = (int*)(PX + (size_t)NN * 2 * CC);  // EE ints      (6.4 MB)
    int*   offs   = elist + EE;                        // NPAD ints
    int*   bsum   = offs + NPAD;                       // 256 ints
    int*   cnt    = bsum + 256;                        // NN ints  -- zeroed
    int*   cur    = cnt + NN;                          // NN ints  -- zeroed
    float* sums   = (float*)(cur + NN);                // 2 layers * 40 f -- zeroed
    float* pooled = sums + 2 * 2 * CC;                 // GG*CC f  -- zeroed

    // one memset covers cnt | cur | sums | pooled (contiguous)
    size_t zbytes = ((size_t)NN + NN + 2*2*CC + (size_t)GG*CC) * sizeof(float);
    hipMemsetAsync(cnt, 0, zbytes, stream);

    // ---- CSR build (reused by both layers) ----
    k_hist<<<(EE + 255) / 256, 256, 0, stream>>>(ei, cnt);
    k_scan_a<<<NB, SCAN_TPB, 0, stream>>>(cnt, offs, bsum);
    k_scan_b<<<1, SCAN_TPB, 0, stream>>>(bsum);
    k_scan_c<<<NPAD / 256, 256, 0, stream>>>(offs, bsum);
    k_fill<<<(EE + 255) / 256, 256, 0, stream>>>(ei, offs, cur, elist);

    const int nblocks = (NN + 255) / 256;
    const int mblocks = (EE / 4 + 255) / 256;   // 1563

    // layer 0
    k_pre0<<<nblocks, 256, 0, stream>>>(x, lfw, lfb, lsw, lsb, P0, PX, y);
    k_msg<<<mblocks, 256, 0, stream>>>(ei, ea, elist, offs, P0, PX,
                                       lfw + 2*CC*CC, lsw + 2*CC*CC, y);
    k_bnstats<<<STAT_BLOCKS, 256, 0, stream>>>(y, sums);
    // BN(l0)+tanh in place, precompute for layer 1
    k_bnpre<<<nblocks, 256, 0, stream>>>(y, sums, bng, bnb,
        lfw + (size_t)KK*CC, lfb + CC, lsw + (size_t)KK*CC, lsb + CC, P0, PX);
    // layer 1
    k_msg<<<mblocks, 256, 0, stream>>>(ei, ea, elist, offs, P0, PX,
        lfw + (size_t)KK*CC + 2*CC*CC, lsw + (size_t)KK*CC + 2*CC*CC, y);
    k_bnstats<<<STAT_BLOCKS, 256, 0, stream>>>(y, sums + 2*CC);
    // BN(l1)+tanh+pool
    k_bnpool<<<nblocks, 256, 0, stream>>>(y, sums + 2*CC, bng + CC, bnb + CC,
                                          bat, pooled);
    k_mlp<<<(GG + 255) / 256, 256, 0, stream>>>(pooled, w1, b1, w2, b2, w3, b3, out);
}

// Round 5
// 616.647 us; speedup vs baseline: 7.3749x; 1.2019x over previous
//
#include <hip/hip_runtime.h>
#include <math.h>

#define NN 100000
#define EE 1600000
#define CC 20
#define DD 8
#define GG 1024
#define LL 2
#define KK (2*CC+DD)   // 48
#define EPSV 1e-5f

#define SCAN_TPB 256
#define SCAN_ELEMS 4
#define NB 98                      // ceil(NN / 1024)
#define NPAD (NB * SCAN_TPB * SCAN_ELEMS)  // 100352

// ---------------- CSR build ----------------
__global__ __launch_bounds__(256) void k_hist(const int* __restrict__ ei,
                                              int* __restrict__ cnt) {
    int t = blockIdx.x * 256 + threadIdx.x;
    if (t * 4 >= EE) return;
    int4 d4 = reinterpret_cast<const int4*>(ei + EE)[t];
    atomicAdd(&cnt[d4.x], 1);
    atomicAdd(&cnt[d4.y], 1);
    atomicAdd(&cnt[d4.z], 1);
    atomicAdd(&cnt[d4.w], 1);
}

__global__ __launch_bounds__(SCAN_TPB) void k_scan_a(const int* __restrict__ cnt,
                                                     int* __restrict__ offs,
                                                     int* __restrict__ bsum) {
    __shared__ int sdata[SCAN_TPB];
    int base = blockIdx.x * (SCAN_TPB * SCAN_ELEMS) + threadIdx.x * SCAN_ELEMS;
    int v[SCAN_ELEMS];
    int tot = 0;
#pragma unroll
    for (int i = 0; i < SCAN_ELEMS; ++i) {
        int idx = base + i;
        v[i] = (idx < NN) ? cnt[idx] : 0;
        tot += v[i];
    }
    sdata[threadIdx.x] = tot;
    __syncthreads();
    for (int o = 1; o < SCAN_TPB; o <<= 1) {
        int t = (threadIdx.x >= o) ? sdata[threadIdx.x - o] : 0;
        __syncthreads();
        sdata[threadIdx.x] += t;
        __syncthreads();
    }
    int run = sdata[threadIdx.x] - tot;  // exclusive prefix of this thread
#pragma unroll
    for (int i = 0; i < SCAN_ELEMS; ++i) {
        offs[base + i] = run;
        run += v[i];
    }
    if (threadIdx.x == SCAN_TPB - 1) bsum[blockIdx.x] = sdata[threadIdx.x];
}

// scan of bsum (redundant per block) + add to offs  (fuses old scan_b+scan_c)
__global__ __launch_bounds__(256) void k_scan_bc(int* __restrict__ offs,
                                                 const int* __restrict__ bsum) {
    __shared__ int sv[SCAN_TPB];
    __shared__ int se[SCAN_TPB];
    int v = (threadIdx.x < NB) ? bsum[threadIdx.x] : 0;
    sv[threadIdx.x] = v;
    __syncthreads();
    for (int o = 1; o < SCAN_TPB; o <<= 1) {
        int t = (threadIdx.x >= o) ? sv[threadIdx.x - o] : 0;
        __syncthreads();
        sv[threadIdx.x] += t;
        __syncthreads();
    }
    se[threadIdx.x] = sv[threadIdx.x] - v;   // exclusive
    __syncthreads();
    int i = blockIdx.x * 256 + threadIdx.x;  // grid = NPAD/256 exactly
    offs[i] += se[blockIdx.x >> 2];          // (i>>10) constant per block
}

// fill: scatter s, d, edge_attr into dst-sorted order
__global__ __launch_bounds__(256) void k_fill(const int* __restrict__ ei,
                                              const float* __restrict__ ea,
                                              const int* __restrict__ offs,
                                              int* __restrict__ cur,
                                              int* __restrict__ es,
                                              int* __restrict__ ds,
                                              float* __restrict__ eas) {
    int e = blockIdx.x * 256 + threadIdx.x;
    if (e >= EE) return;
    int s = ei[e];
    int d = ei[EE + e];
    int pos = offs[d] + atomicAdd(&cur[d], 1);
    es[pos] = s;
    ds[pos] = d;
    const float4* src = reinterpret_cast<const float4*>(ea + (size_t)e * DD);
    float4* dst = reinterpret_cast<float4*>(eas + (size_t)pos * DD);
    dst[0] = src[0];
    dst[1] = src[1];
}

// ---------------- per-node precompute: P0 = [bf + x@Wf[0:20] | bs + x@Ws[0:20]]
//                  PX = [x@Wf[20:40] | x@Ws[20:40]] ; y := x (residual init)
__global__ __launch_bounds__(256) void k_pre0(
    const float* __restrict__ x,
    const float* __restrict__ wf, const float* __restrict__ bf,
    const float* __restrict__ wsm, const float* __restrict__ bs,
    float* __restrict__ P0, float* __restrict__ PX, float* __restrict__ y)
{
    int n = blockIdx.x * 256 + threadIdx.x;
    if (n >= NN) return;
    float xn[CC];
    const float4* xp = reinterpret_cast<const float4*>(x + (size_t)n * CC);
    float4* yp = reinterpret_cast<float4*>(y + (size_t)n * CC);
#pragma unroll
    for (int q = 0; q < 5; ++q) {
        float4 t = xp[q];
        yp[q] = t;
        xn[4*q+0] = t.x; xn[4*q+1] = t.y; xn[4*q+2] = t.z; xn[4*q+3] = t.w;
    }
    float f0[CC], g0[CC], fx[CC], gx[CC];
#pragma unroll
    for (int c = 0; c < CC; ++c) { f0[c] = bf[c]; g0[c] = bs[c]; fx[c] = 0.f; gx[c] = 0.f; }
#pragma unroll
    for (int k = 0; k < CC; ++k) {
        float zk = xn[k];
#pragma unroll
        for (int c = 0; c < CC; ++c) {
            f0[c] = fmaf(zk, wf[k*CC + c], f0[c]);
            g0[c] = fmaf(zk, wsm[k*CC + c], g0[c]);
            fx[c] = fmaf(zk, wf[(CC+k)*CC + c], fx[c]);
            gx[c] = fmaf(zk, wsm[(CC+k)*CC + c], gx[c]);
        }
    }
    float4* pp = reinterpret_cast<float4*>(P0 + (size_t)n * 2*CC);
    float4* px = reinterpret_cast<float4*>(PX + (size_t)n * 2*CC);
#pragma unroll
    for (int q = 0; q < 5; ++q) {
        pp[q]   = make_float4(f0[4*q+0], f0[4*q+1], f0[4*q+2], f0[4*q+3]);
        pp[5+q] = make_float4(g0[4*q+0], g0[4*q+1], g0[4*q+2], g0[4*q+3]);
        px[q]   = make_float4(fx[4*q+0], fx[4*q+1], fx[4*q+2], fx[4*q+3]);
        px[5+q] = make_float4(gx[4*q+0], gx[4*q+1], gx[4*q+2], gx[4*q+3]);
    }
}

// ---------------- BN(prev layer) + tanh in place, then precompute for next layer
__global__ __launch_bounds__(256) void k_bnpre(
    float* __restrict__ y, const float* __restrict__ sums,
    const float* __restrict__ gam, const float* __restrict__ bet,
    const float* __restrict__ wf, const float* __restrict__ bf,
    const float* __restrict__ wsm, const float* __restrict__ bs,
    float* __restrict__ P0, float* __restrict__ PX)
{
    int n = blockIdx.x * 256 + threadIdx.x;
    if (n >= NN) return;
    const float inv = 1.0f / (float)NN;
    float4* yp = reinterpret_cast<float4*>(y + (size_t)n * CC);
    float xn[CC];
#pragma unroll
    for (int q = 0; q < 5; ++q) {
        float4 t = yp[q];
        xn[4*q+0] = t.x; xn[4*q+1] = t.y; xn[4*q+2] = t.z; xn[4*q+3] = t.w;
    }
#pragma unroll
    for (int c = 0; c < CC; ++c) {
        float mean = sums[c] * inv;
        float var  = sums[CC + c] * inv - mean * mean;
        float scale = gam[c] * rsqrtf(var + EPSV);
        float shift = bet[c] - mean * scale;
        xn[c] = tanhf(fmaf(xn[c], scale, shift));
    }
#pragma unroll
    for (int q = 0; q < 5; ++q)
        yp[q] = make_float4(xn[4*q+0], xn[4*q+1], xn[4*q+2], xn[4*q+3]);

    float f0[CC], g0[CC], fx[CC], gx[CC];
#pragma unroll
    for (int c = 0; c < CC; ++c) { f0[c] = bf[c]; g0[c] = bs[c]; fx[c] = 0.f; gx[c] = 0.f; }
#pragma unroll
    for (int k = 0; k < CC; ++k) {
        float zk = xn[k];
#pragma unroll
        for (int c = 0; c < CC; ++c) {
            f0[c] = fmaf(zk, wf[k*CC + c], f0[c]);
            g0[c] = fmaf(zk, wsm[k*CC + c], g0[c]);
            fx[c] = fmaf(zk, wf[(CC+k)*CC + c], fx[c]);
            gx[c] = fmaf(zk, wsm[(CC+k)*CC + c], gx[c]);
        }
    }
    float4* pp = reinterpret_cast<float4*>(P0 + (size_t)n * 2*CC);
    float4* px = reinterpret_cast<float4*>(PX + (size_t)n * 2*CC);
#pragma unroll
    for (int q = 0; q < 5; ++q) {
        pp[q]   = make_float4(f0[4*q+0], f0[4*q+1], f0[4*q+2], f0[4*q+3]);
        pp[5+q] = make_float4(g0[4*q+0], g0[4*q+1], g0[4*q+2], g0[4*q+3]);
        px[q]   = make_float4(fx[4*q+0], fx[4*q+1], fx[4*q+2], fx[4*q+3]);
        px[5+q] = make_float4(gx[4*q+0], gx[4*q+1], gx[4*q+2], gx[4*q+3]);
    }
}

// ---------------- edge message (sorted index i) ----------------
__device__ __forceinline__ void edge_msg(int i, int s, int d,
    const float* __restrict__ eas, const float* __restrict__ P0,
    const float* __restrict__ PX,
    const float* __restrict__ wfe, const float* __restrict__ wse,
    float* m)
{
    const float4* eap = reinterpret_cast<const float4*>(eas + (size_t)i * DD);
    float4 ea0 = eap[0], ea1 = eap[1];
    float eaw[8] = {ea0.x, ea0.y, ea0.z, ea0.w, ea1.x, ea1.y, ea1.z, ea1.w};
    const float4* p0 = reinterpret_cast<const float4*>(P0 + (size_t)d * 2*CC);
    const float4* px = reinterpret_cast<const float4*>(PX + (size_t)s * 2*CC);
    float f[CC], g[CC];
#pragma unroll
    for (int q = 0; q < 5; ++q) {
        float4 a = p0[q], b = px[q];
        f[4*q+0] = a.x + b.x; f[4*q+1] = a.y + b.y;
        f[4*q+2] = a.z + b.z; f[4*q+3] = a.w + b.w;
    }
#pragma unroll
    for (int q = 0; q < 5; ++q) {
        float4 a = p0[5+q], b = px[5+q];
        g[4*q+0] = a.x + b.x; g[4*q+1] = a.y + b.y;
        g[4*q+2] = a.z + b.z; g[4*q+3] = a.w + b.w;
    }
#pragma unroll
    for (int k = 0; k < 8; ++k) {
        float zk = eaw[k];
#pragma unroll
        for (int c = 0; c < CC; ++c) {
            f[c] = fmaf(zk, wfe[k*CC + c], f[c]);
            g[c] = fmaf(zk, wse[k*CC + c], g[c]);
        }
    }
#pragma unroll
    for (int c = 0; c < CC; ++c) {
        float sg = 1.0f / (1.0f + __expf(-f[c]));
        float sp = fmaxf(g[c], 0.0f) + __logf(1.0f + __expf(-fabsf(g[c])));
        m[c] = sg * sp;
    }
}

__device__ __forceinline__ void commit(float* __restrict__ y, int d,
                                       const float* acc, bool complete) {
    float* yp = y + (size_t)d * CC;
    if (complete) {
        float4* y4 = reinterpret_cast<float4*>(yp);
#pragma unroll
        for (int q = 0; q < 5; ++q) {
            float4 t = y4[q];
            t.x += acc[4*q+0]; t.y += acc[4*q+1];
            t.z += acc[4*q+2]; t.w += acc[4*q+3];
            y4[q] = t;
        }
    } else {
#pragma unroll
        for (int c = 0; c < CC; ++c) atomicAdd(yp + c, acc[c]);
    }
}

// ---------------- fused edge kernel: 4 sorted edges/thread, wave seg-reduce ----------------
__global__ __launch_bounds__(256) void k_msg(
    const int* __restrict__ es, const int* __restrict__ ds,
    const float* __restrict__ eas, const int* __restrict__ offs,
    const float* __restrict__ P0, const float* __restrict__ PX,
    const float* __restrict__ wfe, const float* __restrict__ wse,
    float* __restrict__ y)
{
    int t = blockIdx.x * 256 + threadIdx.x;
    int i0 = t * 4;
    if (i0 >= EE) return;               // whole-wave uniform exit (EE/4 % 64 == 0)
    int lane = threadIdx.x & 63;
    int W = i0 & ~255;                  // wave's first sorted-edge index

    int4 sv4 = reinterpret_cast<const int4*>(es)[t];
    int4 dv4 = reinterpret_cast<const int4*>(ds)[t];
    int s_[4] = {sv4.x, sv4.y, sv4.z, sv4.w};
    int d_[4] = {dv4.x, dv4.y, dv4.z, dv4.w};

    float trail[CC], lead[CC], m[CC];
    int trail_d, lead_d = -1;

    edge_msg(i0, s_[0], d_[0], eas, P0, PX, wfe, wse, trail);
    trail_d = d_[0];
#pragma unroll
    for (int j = 1; j < 4; ++j) {
        edge_msg(i0 + j, s_[j], d_[j], eas, P0, PX, wfe, wse, m);
        if (d_[j] == trail_d) {
#pragma unroll
            for (int c = 0; c < CC; ++c) trail[c] += m[c];
        } else {
            if (lead_d < 0) {
#pragma unroll
                for (int c = 0; c < CC; ++c) lead[c] = trail[c];
                lead_d = trail_d;
            } else {
                commit(y, trail_d, trail, true);   // run fully inside thread
            }
#pragma unroll
            for (int c = 0; c < CC; ++c) trail[c] = m[c];
            trail_d = d_[j];
        }
    }

    // segmented inclusive scan of trail across lanes (d monotone -> simple pred)
    float mk[6];
#pragma unroll
    for (int k = 0; k < 6; ++k) {
        int off = 1 << k;
        int dfrom = __shfl_up(trail_d, off);
        mk[k] = (lane >= off && dfrom == trail_d) ? 1.0f : 0.0f;
    }
#pragma unroll
    for (int k = 0; k < 6; ++k) {
        int off = 1 << k;
#pragma unroll
        for (int c = 0; c < CC; ++c) {
            float tt = __shfl_up(trail[c], off);
            trail[c] = fmaf(tt, mk[k], trail[c]);
        }
    }
    int dt_next = __shfl_down(trail_d, 1);
    int ld_next = __shfl_down(lead_d, 1);
    // incoming chain for this thread's leading run (from scanned trail of lane-1)
    int d_prev = __shfl_up(trail_d, 1);
    float gate = (lane > 0 && d_prev == lead_d) ? 1.0f : 0.0f;
#pragma unroll
    for (int c = 0; c < CC; ++c) {
        float tt = __shfl_up(trail[c], 1);
        lead[c] = fmaf(tt, gate, lead[c]);
    }

    bool tail = (lane == 63) || (dt_next != trail_d && ld_next != trail_d);
    if (tail) {
        int o0 = offs[trail_d], o1 = offs[trail_d + 1];
        bool complete = (o0 >= W) && (o1 == i0 + 4);
        commit(y, trail_d, trail, complete);
    }
    if (lead_d >= 0) {
        int o0 = offs[lead_d];
        commit(y, lead_d, lead, o0 >= W);   // run ends mid-thread -> within wave
    }
}

// ---------------- BN stats: grid-stride, block-level reduction ----------------
#define STAT_BLOCKS 128
__global__ __launch_bounds__(256) void k_bnstats(const float* __restrict__ y,
                                                 float* __restrict__ sums)
{
    __shared__ float ls[4][2 * CC];
    float s0[CC], s1[CC];
#pragma unroll
    for (int c = 0; c < CC; ++c) { s0[c] = 0.0f; s1[c] = 0.0f; }
    for (int n = blockIdx.x * 256 + threadIdx.x; n < NN; n += STAT_BLOCKS * 256) {
        const float4* p = reinterpret_cast<const float4*>(y + (size_t)n * CC);
#pragma unroll
        for (int q = 0; q < 5; ++q) {
            float4 t = p[q];
            s0[4*q+0] += t.x; s1[4*q+0] += t.x * t.x;
            s0[4*q+1] += t.y; s1[4*q+1] += t.y * t.y;
            s0[4*q+2] += t.z; s1[4*q+2] += t.z * t.z;
            s0[4*q+3] += t.w; s1[4*q+3] += t.w * t.w;
        }
    }
    int lane = threadIdx.x & 63;
    int wave = threadIdx.x >> 6;
#pragma unroll
    for (int c = 0; c < CC; ++c) {
        float a = s0[c], b = s1[c];
        for (int o = 32; o > 0; o >>= 1) {
            a += __shfl_down(a, o);
            b += __shfl_down(b, o);
        }
        if (lane == 0) { ls[wave][c] = a; ls[wave][CC + c] = b; }
    }
    __syncthreads();
    if (threadIdx.x < 2 * CC) {
        float tot = ls[0][threadIdx.x] + ls[1][threadIdx.x] +
                    ls[2][threadIdx.x] + ls[3][threadIdx.x];
        atomicAdd(&sums[threadIdx.x], tot);
    }
}

// ---------------- final: BN + tanh + global_add_pool ----------------
__global__ __launch_bounds__(256) void k_bnpool(
    const float* __restrict__ y, const float* __restrict__ sums,
    const float* __restrict__ gam, const float* __restrict__ bet,
    const int* __restrict__ batch, float* __restrict__ pooled)
{
    int n = blockIdx.x * 256 + threadIdx.x;
    int nc = n < NN ? n : NN - 1;
    bool valid = n < NN;
    int g = batch[nc];
    const float inv = 1.0f / (float)NN;
    float v[CC];
    const float4* p = reinterpret_cast<const float4*>(y + (size_t)nc * CC);
#pragma unroll
    for (int q = 0; q < 5; ++q) {
        float4 t = p[q];
        v[4*q+0] = t.x; v[4*q+1] = t.y; v[4*q+2] = t.z; v[4*q+3] = t.w;
    }
#pragma unroll
    for (int c = 0; c < CC; ++c) {
        float mean = sums[c] * inv;
        float var  = sums[CC + c] * inv - mean * mean;
        float scale = gam[c] * rsqrtf(var + EPSV);
        float shift = bet[c] - mean * scale;
        v[c] = tanhf(fmaf(v[c], scale, shift));
        if (!valid) v[c] = 0.0f;
    }
    int lane = threadIdx.x & 63;
    int g0 = __shfl(g, 0);
    if (__all(g == g0)) {
#pragma unroll
        for (int c = 0; c < CC; ++c) {
            float a = v[c];
            for (int o = 32; o > 0; o >>= 1) a += __shfl_down(a, o);
            if (lane == 0) atomicAdd(&pooled[(size_t)g0 * CC + c], a);
        }
    } else if (valid) {
#pragma unroll
        for (int c = 0; c < CC; ++c) atomicAdd(&pooled[(size_t)g * CC + c], v[c]);
    }
}

// ---------------- final MLP ----------------
__global__ __launch_bounds__(256) void k_mlp(const float* __restrict__ pooled,
    const float* __restrict__ w1, const float* __restrict__ b1,
    const float* __restrict__ w2, const float* __restrict__ b2,
    const float* __restrict__ w3, const float* __restrict__ b3,
    float* __restrict__ out)
{
    int gi = blockIdx.x * 256 + threadIdx.x;
    if (gi >= GG) return;

    float p[CC];
    const float4* pp = reinterpret_cast<const float4*>(pooled + (size_t)gi * CC);
#pragma unroll
    for (int q = 0; q < 5; ++q) {
        float4 t = pp[q];
        p[4*q+0] = t.x; p[4*q+1] = t.y; p[4*q+2] = t.z; p[4*q+3] = t.w;
    }
    float h1[32];
#pragma unroll
    for (int j = 0; j < 32; ++j) h1[j] = b1[j];
#pragma unroll
    for (int c = 0; c < CC; ++c) {
        float pc = p[c];
#pragma unroll
        for (int j = 0; j < 32; ++j) h1[j] = fmaf(pc, w1[c*32 + j], h1[j]);
    }
#pragma unroll
    for (int j = 0; j < 32; ++j) h1[j] = tanhf(h1[j]);
    float h2[8];
#pragma unroll
    for (int j = 0; j < 8; ++j) h2[j] = b2[j];
#pragma unroll
    for (int c = 0; c < 32; ++c) {
        float hc = h1[c];
#pragma unroll
        for (int j = 0; j < 8; ++j) h2[j] = fmaf(hc, w2[c*8 + j], h2[j]);
    }
    float o = b3[0];
#pragma unroll
    for (int j = 0; j < 8; ++j) o = fmaf(tanhf(h2[j]), w3[j], o);
    out[gi] = o;
}

extern "C" void kernel_launch(void* const* d_in, const int* in_sizes, int n_in,
                              void* d_out, int out_size, void* d_ws, size_t ws_size,
                              hipStream_t stream) {
    const float* x   = (const float*)d_in[0];
    const int*   ei  = (const int*)d_in[1];
    const float* ea  = (const float*)d_in[2];
    const int*   bat = (const int*)d_in[3];
    const float* lfw = (const float*)d_in[4];
    const float* lfb = (const float*)d_in[5];
    const float* lsw = (const float*)d_in[6];
    const float* lsb = (const float*)d_in[7];
    const float* bng = (const float*)d_in[8];
    const float* bnb = (const float*)d_in[9];
    const float* w1  = (const float*)d_in[10];
    const float* b1  = (const float*)d_in[11];
    const float* w2  = (const float*)d_in[12];
    const float* b2  = (const float*)d_in[13];
    const float* w3  = (const float*)d_in[14];
    const float* b3  = (const float*)d_in[15];
    float* out = (float*)d_out;

    char* ws = (char*)d_ws;
    float* y      = (float*)ws;                        // NN*20 f      (8 MB)
    float* P0     = y + (size_t)NN * CC;               // NN*40 f      (16 MB)
    float* PX     = P0 + (size_t)NN * 2 * CC;          // NN*40 f      (16 MB)
    float* eas    = PX + (size_t)NN * 2 * CC;          // EE*8 f       (51.2 MB)
    int*   es     = (int*)(eas + (size_t)EE * DD);     // EE ints      (6.4 MB)
    int*   ds     = es + EE;                           // EE ints      (6.4 MB)
    int*   offs   = ds + EE;                           // NPAD ints
    int*   bsum   = offs + NPAD;                       // 256 ints
    int*   cnt    = bsum + 256;                        // NN ints  -- zeroed
    int*   cur    = cnt + NN;                          // NN ints  -- zeroed
    float* sums   = (float*)(cur + NN);                // 2 layers * 40 f -- zeroed
    float* pooled = sums + 2 * 2 * CC;                 // GG*CC f  -- zeroed

    // one memset covers cnt | cur | sums | pooled (contiguous)
    size_t zbytes = ((size_t)NN + NN + 2*2*CC + (size_t)GG*CC) * sizeof(float);
    hipMemsetAsync(cnt, 0, zbytes, stream);

    // ---- CSR build + payload sort (reused by both layers) ----
    k_hist<<<(EE/4 + 255) / 256, 256, 0, stream>>>(ei, cnt);
    k_scan_a<<<NB, SCAN_TPB, 0, stream>>>(cnt, offs, bsum);
    k_scan_bc<<<NPAD / 256, 256, 0, stream>>>(offs, bsum);
    k_fill<<<(EE + 255) / 256, 256, 0, stream>>>(ei, ea, offs, cur, es, ds, eas);

    const int nblocks = (NN + 255) / 256;
    const int mblocks = (EE / 4 + 255) / 256;   // 1563

    // layer 0
    k_pre0<<<nblocks, 256, 0, stream>>>(x, lfw, lfb, lsw, lsb, P0, PX, y);
    k_msg<<<mblocks, 256, 0, stream>>>(es, ds, eas, offs, P0, PX,
                                       lfw + 2*CC*CC, lsw + 2*CC*CC, y);
    k_bnstats<<<STAT_BLOCKS, 256, 0, stream>>>(y, sums);
    // BN(l0)+tanh in place, precompute for layer 1
    k_bnpre<<<nblocks, 256, 0, stream>>>(y, sums, bng, bnb,
        lfw + (size_t)KK*CC, lfb + CC, lsw + (size_t)KK*CC, lsb + CC, P0, PX);
    // layer 1
    k_msg<<<mblocks, 256, 0, stream>>>(es, ds, eas, offs, P0, PX,
        lfw + (size_t)KK*CC + 2*CC*CC, lsw + (size_t)KK*CC + 2*CC*CC, y);
    k_bnstats<<<STAT_BLOCKS, 256, 0, stream>>>(y, sums + 2*CC);
    // BN(l1)+tanh+pool
    k_bnpool<<<nblocks, 256, 0, stream>>>(y, sums + 2*CC, bng + CC, bnb + CC,
                                          bat, pooled);
    k_mlp<<<(GG + 255) / 256, 256, 0, stream>>>(pooled, w1, b1, w2, b2, w3, b3, out);
}